// Round 2
// baseline (726.372 us; speedup 1.0000x reference)
//
#include <hip/hip_runtime.h>

typedef _Float16 f16;
typedef __attribute__((ext_vector_type(8))) _Float16 half8;   // MFMA A/B frag (4 VGPRs)
typedef __attribute__((ext_vector_type(4))) _Float16 half4;   // 8-byte LDS store
typedef __attribute__((ext_vector_type(4))) float   f4;       // MFMA C/D

#define NTOK   196
#define MROWS  50176            // 256 * 196
#define HIDN   1536
#define HPC    192              // per-head channels in h (q32|k32|v128)
#define DHD    1024             // H * 128
#define EPSV   1e-5f
#define SCALEV 0.17677669529663687f

// ---------------- GEMM1: h = x @ Wqkv^T  (f32 in, f16 compute, f16 out + BN stats)
__global__ __launch_bounds__(256) void gemm1_qkv(
    const float* __restrict__ A, const float* __restrict__ B,
    f16* __restrict__ C, float* __restrict__ gsum, float* __restrict__ gsq)
{
    const int K = 256, ldc = HIDN;
    __shared__ f16 As[128][40];
    __shared__ f16 Bs[128][40];
    __shared__ float ssum[128], ssq[128];

    const int t = threadIdx.x;
    const int m0 = blockIdx.x * 128, n0 = blockIdx.y * 128;
    const int wid = t >> 6, lane = t & 63, quad = lane >> 4, lm = lane & 15;
    const int wm = (wid >> 1) * 64, wn = (wid & 1) * 64;

    f4 acc[4][4] = {};

    for (int k0 = 0; k0 < K; k0 += 32) {
        #pragma unroll
        for (int s = 0; s < 4; ++s) {
            int ch = t + s * 256;              // 0..1023
            int r = ch >> 3, c4 = (ch & 7) * 4;
            float4 va = *(const float4*)&A[(long)(m0 + r) * K + k0 + c4];
            float4 vb = *(const float4*)&B[(long)(n0 + r) * K + k0 + c4];
            half4 ha = { (f16)va.x, (f16)va.y, (f16)va.z, (f16)va.w };
            half4 hb = { (f16)vb.x, (f16)vb.y, (f16)vb.z, (f16)vb.w };
            *(half4*)&As[r][c4] = ha;
            *(half4*)&Bs[r][c4] = hb;
        }
        __syncthreads();
        half8 a[4], b[4];
        #pragma unroll
        for (int i = 0; i < 4; ++i) a[i] = *(const half8*)&As[wm + i*16 + lm][quad*8];
        #pragma unroll
        for (int j = 0; j < 4; ++j) b[j] = *(const half8*)&Bs[wn + j*16 + lm][quad*8];
        #pragma unroll
        for (int i = 0; i < 4; ++i)
            #pragma unroll
            for (int j = 0; j < 4; ++j)
                acc[i][j] = __builtin_amdgcn_mfma_f32_16x16x32_f16(a[i], b[j], acc[i][j], 0, 0, 0);
        __syncthreads();
    }

    if (t < 128) { ssum[t] = 0.f; ssq[t] = 0.f; }
    __syncthreads();

    #pragma unroll
    for (int j = 0; j < 4; ++j) {
        int nl = wn + j*16 + lm;
        float psum = 0.f, psq = 0.f;
        #pragma unroll
        for (int i = 0; i < 4; ++i) {
            #pragma unroll
            for (int r = 0; r < 4; ++r) {
                int ml = wm + i*16 + quad*4 + r;
                float v = acc[i][j][r];
                f16 uh = (f16)v;
                float vb = (float)uh;                     // stats from stored value
                C[(long)(m0 + ml) * ldc + n0 + nl] = uh;
                psum += vb; psq += vb * vb;
            }
        }
        atomicAdd(&ssum[nl], psum);
        atomicAdd(&ssq[nl], psq);
    }
    __syncthreads();
    if (t < 128) {
        atomicAdd(&gsum[n0 + t], ssum[t]);
        atomicAdd(&gsq[n0 + t],  ssq[t]);
    }
}

// ---------------- GEMM2: p = o @ Wproj^T  (f16 A, f32 B, f32 out + BN stats)
__global__ __launch_bounds__(256) void gemm2_proj(
    const f16* __restrict__ A, const float* __restrict__ B,
    float* __restrict__ C, float* __restrict__ gsum, float* __restrict__ gsq)
{
    const int K = 1024, ldc = 256;
    __shared__ f16 As[128][40];
    __shared__ f16 Bs[128][40];
    __shared__ float ssum[128], ssq[128];

    const int t = threadIdx.x;
    const int m0 = blockIdx.x * 128, n0 = blockIdx.y * 128;
    const int wid = t >> 6, lane = t & 63, quad = lane >> 4, lm = lane & 15;
    const int wm = (wid >> 1) * 64, wn = (wid & 1) * 64;

    f4 acc[4][4] = {};

    for (int k0 = 0; k0 < K; k0 += 32) {
        #pragma unroll
        for (int s = 0; s < 2; ++s) {          // A: f16 direct 16B copies
            int ch = t + s * 256;              // 0..511
            int r = ch >> 2, c8 = (ch & 3) * 8;
            *(half8*)&As[r][c8] = *(const half8*)&A[(long)(m0 + r) * K + k0 + c8];
        }
        #pragma unroll
        for (int s = 0; s < 4; ++s) {          // B: f32 load + convert
            int ch = t + s * 256;
            int r = ch >> 3, c4 = (ch & 7) * 4;
            float4 vb = *(const float4*)&B[(long)(n0 + r) * K + k0 + c4];
            half4 hb = { (f16)vb.x, (f16)vb.y, (f16)vb.z, (f16)vb.w };
            *(half4*)&Bs[r][c4] = hb;
        }
        __syncthreads();
        half8 a[4], b[4];
        #pragma unroll
        for (int i = 0; i < 4; ++i) a[i] = *(const half8*)&As[wm + i*16 + lm][quad*8];
        #pragma unroll
        for (int j = 0; j < 4; ++j) b[j] = *(const half8*)&Bs[wn + j*16 + lm][quad*8];
        #pragma unroll
        for (int i = 0; i < 4; ++i)
            #pragma unroll
            for (int j = 0; j < 4; ++j)
                acc[i][j] = __builtin_amdgcn_mfma_f32_16x16x32_f16(a[i], b[j], acc[i][j], 0, 0, 0);
        __syncthreads();
    }

    if (t < 128) { ssum[t] = 0.f; ssq[t] = 0.f; }
    __syncthreads();

    #pragma unroll
    for (int j = 0; j < 4; ++j) {
        int nl = wn + j*16 + lm;
        float psum = 0.f, psq = 0.f;
        #pragma unroll
        for (int i = 0; i < 4; ++i) {
            #pragma unroll
            for (int r = 0; r < 4; ++r) {
                int ml = wm + i*16 + quad*4 + r;
                float v = acc[i][j][r];
                C[(long)(m0 + ml) * ldc + n0 + nl] = v;
                psum += v; psq += v * v;
            }
        }
        atomicAdd(&ssum[nl], psum);
        atomicAdd(&ssq[nl], psq);
    }
    __syncthreads();
    if (t < 128) {
        atomicAdd(&gsum[n0 + t], ssum[t]);
        atomicAdd(&gsq[n0 + t],  ssq[t]);
    }
}

__global__ void bn_fin(const float* __restrict__ gsum, const float* __restrict__ gsq,
                       const float* __restrict__ g, const float* __restrict__ b,
                       float* __restrict__ a_out, float* __restrict__ s_out, int nch)
{
    int c = blockIdx.x * blockDim.x + threadIdx.x;
    if (c >= nch) return;
    float inv  = 1.f / (float)MROWS;
    float mean = gsum[c] * inv;
    float var  = gsq[c] * inv - mean * mean;
    float a    = g[c] * rsqrtf(var + EPSV);
    a_out[c] = a;
    s_out[c] = b[c] - mean * a;
}

// ---------------- attention: one block per (batch, head)
__global__ __launch_bounds__(256) void attn_kernel(
    const f16* __restrict__ hbuf, const float* __restrict__ a1, const float* __restrict__ s1,
    const float* __restrict__ bias_table, const int* __restrict__ idxs,
    f16* __restrict__ obuf)
{
    __shared__ f16   qs[208][40];   // queries (pad rows zeroed)
    __shared__ f16   ks[224][40];   // keys    (pad rows zeroed)
    __shared__ f16   vT[128][232];  // v transposed: [channel][key] (pad cols zeroed)
    __shared__ float sbuf[16][224]; // one 16-row S block (f32)
    __shared__ f16   ps[16][232];   // P in f16
    __shared__ float biasr[196];
    __shared__ float af[192], sf[192];

    const int t  = threadIdx.x;
    const int bb = blockIdx.x >> 3;
    const int hh = blockIdx.x & 7;
    const int wid = t >> 6, lane = t & 63, quad = lane >> 4, lm = lane & 15;

    if (t < 192) { af[t] = a1[hh * HPC + t]; sf[t] = s1[hh * HPC + t]; }
    if (t < 196) { biasr[t] = bias_table[hh * 196 + t]; }
    for (int i = t; i < 12  * 40; i += 256) qs[196 + i / 40][i % 40] = (f16)0.f;
    for (int i = t; i < 28  * 40; i += 256) ks[196 + i / 40][i % 40] = (f16)0.f;
    for (int i = t; i < 128 * 28; i += 256) vT[i / 28][196 + (i % 28)] = (f16)0.f;
    __syncthreads();

    {
        int t8 = t & 7;
        for (int rr = t >> 3; rr < NTOK; rr += 32) {
            const f16* hrow = hbuf + (long)(bb * NTOK + rr) * HIDN + hh * HPC;
            #pragma unroll
            for (int cc = 0; cc < 3; ++cc) {
                int cb = (t8 + cc * 8) * 8;   // 0..184 step 8
                half8 raw = *(const half8*)(hrow + cb);
                f16 ov[8];
                #pragma unroll
                for (int e = 0; e < 8; ++e)
                    ov[e] = (f16)((float)raw[e] * af[cb + e] + sf[cb + e]);
                if (cb < 32) {
                    #pragma unroll
                    for (int e = 0; e < 8; ++e) qs[rr][cb + e] = ov[e];
                } else if (cb < 64) {
                    #pragma unroll
                    for (int e = 0; e < 8; ++e) ks[rr][cb - 32 + e] = ov[e];
                } else {
                    #pragma unroll
                    for (int e = 0; e < 8; ++e) vT[cb - 64 + e][rr] = ov[e];
                }
            }
        }
    }
    __syncthreads();

    for (int mt = 0; mt < 13; ++mt) {
        // ---- Phase A: S = q k^T * scale + bias
        half8 aq = *(const half8*)&qs[mt * 16 + lm][quad * 8];
        for (int nt = wid; nt < 14; nt += 4) {
            half8 bk = *(const half8*)&ks[nt * 16 + lm][quad * 8];
            f4 sa = {};
            sa = __builtin_amdgcn_mfma_f32_16x16x32_f16(aq, bk, sa, 0, 0, 0);
            int kcol = nt * 16 + lm;
            int ksafe = kcol < 196 ? kcol : 195;
            #pragma unroll
            for (int r = 0; r < 4; ++r) {
                int qrl  = quad * 4 + r;
                int qrow = mt * 16 + qrl;
                int qsafe = qrow < 196 ? qrow : 195;
                float bias_v = biasr[idxs[qsafe * 196 + ksafe]];
                float s = sa[r] * SCALEV + bias_v;
                if (kcol >= 196) s = -1e30f;
                sbuf[qrl][kcol] = s;
            }
        }
        __syncthreads();

        // ---- Phase B: softmax (16 threads per row)
        {
            int r = t >> 4, c0 = t & 15;
            float mx = -1e30f;
            #pragma unroll
            for (int ii = 0; ii < 14; ++ii) mx = fmaxf(mx, sbuf[r][c0 + ii * 16]);
            #pragma unroll
            for (int m = 1; m < 16; m <<= 1) mx = fmaxf(mx, __shfl_xor(mx, m, 16));
            float ev[14], sum = 0.f;
            #pragma unroll
            for (int ii = 0; ii < 14; ++ii) {
                float e = __expf(sbuf[r][c0 + ii * 16] - mx);
                ev[ii] = e; sum += e;
            }
            #pragma unroll
            for (int m = 1; m < 16; m <<= 1) sum += __shfl_xor(sum, m, 16);
            float rinv = 1.f / sum;
            #pragma unroll
            for (int ii = 0; ii < 14; ++ii) ps[r][c0 + ii * 16] = (f16)(ev[ii] * rinv);
        }
        __syncthreads();

        // ---- Phase C: O = P V, hard-swish fused
        #pragma unroll
        for (int ct = 0; ct < 2; ++ct) {
            int ctile = wid * 2 + ct;
            f4 oa = {};
            #pragma unroll
            for (int ksx = 0; ksx < 7; ++ksx) {
                half8 ap = *(const half8*)&ps[lm][ksx * 32 + quad * 8];
                half8 bv = *(const half8*)&vT[ctile * 16 + lm][ksx * 32 + quad * 8];
                oa = __builtin_amdgcn_mfma_f32_16x16x32_f16(ap, bv, oa, 0, 0, 0);
            }
            #pragma unroll
            for (int r = 0; r < 4; ++r) {
                int qrow = mt * 16 + quad * 4 + r;
                if (qrow < 196) {
                    float v  = oa[r];
                    float hs = v * fminf(fmaxf(v + 3.f, 0.f), 6.f) * (1.f / 6.f);
                    obuf[(long)(bb * NTOK + qrow) * DHD + hh * 128 + ctile * 16 + lm] = (f16)hs;
                }
            }
        }
        __syncthreads();
    }
}

__global__ __launch_bounds__(256) void bn_apply(
    float* __restrict__ out, const float* __restrict__ a2, const float* __restrict__ s2)
{
    __shared__ float aL[256], sL[256];
    int t = threadIdx.x;
    aL[t] = a2[t]; sL[t] = s2[t];
    __syncthreads();
    long total = (long)MROWS * 256 / 4;
    for (long i = (long)blockIdx.x * 256 + t; i < total; i += (long)gridDim.x * 256) {
        float4 v = *(float4*)&out[i * 4];
        int cb = (int)((i * 4) & 255);
        v.x = v.x * aL[cb + 0] + sL[cb + 0];
        v.y = v.y * aL[cb + 1] + sL[cb + 1];
        v.z = v.z * aL[cb + 2] + sL[cb + 2];
        v.w = v.w * aL[cb + 3] + sL[cb + 3];
        *(float4*)&out[i * 4] = v;
    }
}

extern "C" void kernel_launch(void* const* d_in, const int* in_sizes, int n_in,
                              void* d_out, int out_size, void* d_ws, size_t ws_size,
                              hipStream_t stream)
{
    (void)in_sizes; (void)n_in; (void)out_size; (void)ws_size;
    const float* x          = (const float*)d_in[0];
    const float* Wqkv       = (const float*)d_in[1];
    const float* g1         = (const float*)d_in[2];
    const float* b1         = (const float*)d_in[3];
    const float* bias_table = (const float*)d_in[4];
    const float* Wproj      = (const float*)d_in[5];
    const float* g2         = (const float*)d_in[6];
    const float* b2         = (const float*)d_in[7];
    const int*   idxs       = (const int*)d_in[8];
    float*       out        = (float*)d_out;

    char* ws = (char*)d_ws;
    f16* hbuf = (f16*)ws;                                // 50176*1536*2 = 154,140,672 B
    f16* obuf = (f16*)(ws + 154140672LL);                // 50176*1024*2 = 102,760,448 B
    float* stats = (float*)(ws + 256901120LL);
    float* gsum1 = stats;            float* gsq1 = stats + 1536;
    float* gsum2 = stats + 3072;     float* gsq2 = stats + 3328;
    float* a1 = stats + 3584;        float* s1 = a1 + 1536;
    float* a2 = s1 + 1536;           float* s2 = a2 + 256;

    hipMemsetAsync(stats, 0, 3584 * sizeof(float), stream);

    gemm1_qkv<<<dim3(392, 12), 256, 0, stream>>>(x, Wqkv, hbuf, gsum1, gsq1);
    bn_fin<<<6, 256, 0, stream>>>(gsum1, gsq1, g1, b1, a1, s1, 1536);

    attn_kernel<<<2048, 256, 0, stream>>>(hbuf, a1, s1, bias_table, idxs, obuf);

    gemm2_proj<<<dim3(392, 2), 256, 0, stream>>>(obuf, Wproj, out, gsum2, gsq2);
    bn_fin<<<1, 256, 0, stream>>>(gsum2, gsq2, g2, b2, a2, s2, 256);

    bn_apply<<<1024, 256, 0, stream>>>(out, a2, s2);
}

// Round 3
// 511.684 us; speedup vs baseline: 1.4196x; 1.4196x over previous
//
#include <hip/hip_runtime.h>

typedef _Float16 f16;
typedef __attribute__((ext_vector_type(8))) _Float16 half8;   // MFMA A/B frag (4 VGPRs)
typedef __attribute__((ext_vector_type(4))) _Float16 half4;
typedef __attribute__((ext_vector_type(4))) float   f4;       // MFMA C/D

#define NTOK   196
#define MROWS  50176            // 256 * 196
#define HIDN   1536
#define HPC    192              // per-head channels in h (q32|k32|v128)
#define DHD    1024             // H * 128
#define EPSV   1e-5f
#define SCALEV 0.17677669529663687f

// ---------------- f32 -> f16 convert (vectorized)
__global__ void cvt_f32_f16(const float* __restrict__ src, f16* __restrict__ dst, int n4)
{
    int i = blockIdx.x * blockDim.x + threadIdx.x;
    if (i < n4) {
        float4 v = *(const float4*)&src[i * 4];
        half4 h = { (f16)v.x, (f16)v.y, (f16)v.z, (f16)v.w };
        *(half4*)&dst[i * 4] = h;
    }
}

// ---------------- GEMM1: h = x @ Wqkv^T  (f16 in, f16 out + BN stats)
__global__ __launch_bounds__(256) void gemm1_qkv(
    const f16* __restrict__ A, const f16* __restrict__ B,
    f16* __restrict__ C, float* __restrict__ gsum, float* __restrict__ gsq)
{
    const int K = 256, ldc = HIDN;
    __shared__ f16 As[128][40];
    __shared__ f16 Bs[128][40];
    __shared__ float ssum[128], ssq[128];

    const int t = threadIdx.x;
    const int m0 = blockIdx.x * 128, n0 = blockIdx.y * 128;
    const int wid = t >> 6, lane = t & 63, quad = lane >> 4, lm = lane & 15;
    const int wm = (wid >> 1) * 64, wn = (wid & 1) * 64;

    f4 acc[4][4] = {};

    for (int k0 = 0; k0 < K; k0 += 32) {
        #pragma unroll
        for (int s = 0; s < 2; ++s) {
            int ch = t + s * 256;              // 0..511
            int r = ch >> 2, c8 = (ch & 3) * 8;
            *(half8*)&As[r][c8] = *(const half8*)&A[(long)(m0 + r) * K + k0 + c8];
            *(half8*)&Bs[r][c8] = *(const half8*)&B[(long)(n0 + r) * K + k0 + c8];
        }
        __syncthreads();
        half8 a[4], b[4];
        #pragma unroll
        for (int i = 0; i < 4; ++i) a[i] = *(const half8*)&As[wm + i*16 + lm][quad*8];
        #pragma unroll
        for (int j = 0; j < 4; ++j) b[j] = *(const half8*)&Bs[wn + j*16 + lm][quad*8];
        #pragma unroll
        for (int i = 0; i < 4; ++i)
            #pragma unroll
            for (int j = 0; j < 4; ++j)
                acc[i][j] = __builtin_amdgcn_mfma_f32_16x16x32_f16(a[i], b[j], acc[i][j], 0, 0, 0);
        __syncthreads();
    }

    if (t < 128) { ssum[t] = 0.f; ssq[t] = 0.f; }
    __syncthreads();

    #pragma unroll
    for (int j = 0; j < 4; ++j) {
        int nl = wn + j*16 + lm;
        float psum = 0.f, psq = 0.f;
        #pragma unroll
        for (int i = 0; i < 4; ++i) {
            #pragma unroll
            for (int r = 0; r < 4; ++r) {
                int ml = wm + i*16 + quad*4 + r;
                float v = acc[i][j][r];
                f16 uh = (f16)v;
                float vb = (float)uh;
                C[(long)(m0 + ml) * ldc + n0 + nl] = uh;
                psum += vb; psq += vb * vb;
            }
        }
        atomicAdd(&ssum[nl], psum);
        atomicAdd(&ssq[nl], psq);
    }
    __syncthreads();
    if (t < 128) {
        atomicAdd(&gsum[n0 + t], ssum[t]);
        atomicAdd(&gsq[n0 + t],  ssq[t]);
    }
}

// ---------------- GEMM2: p = o @ Wproj^T  (f16 in, f32 out + BN stats)
__global__ __launch_bounds__(256) void gemm2_proj(
    const f16* __restrict__ A, const f16* __restrict__ B,
    float* __restrict__ C, float* __restrict__ gsum, float* __restrict__ gsq)
{
    const int K = 1024, ldc = 256;
    __shared__ f16 As[128][40];
    __shared__ f16 Bs[128][40];
    __shared__ float ssum[128], ssq[128];

    const int t = threadIdx.x;
    const int m0 = blockIdx.x * 128, n0 = blockIdx.y * 128;
    const int wid = t >> 6, lane = t & 63, quad = lane >> 4, lm = lane & 15;
    const int wm = (wid >> 1) * 64, wn = (wid & 1) * 64;

    f4 acc[4][4] = {};

    for (int k0 = 0; k0 < K; k0 += 32) {
        #pragma unroll
        for (int s = 0; s < 2; ++s) {
            int ch = t + s * 256;
            int r = ch >> 2, c8 = (ch & 3) * 8;
            *(half8*)&As[r][c8] = *(const half8*)&A[(long)(m0 + r) * K + k0 + c8];
            *(half8*)&Bs[r][c8] = *(const half8*)&B[(long)(n0 + r) * K + k0 + c8];
        }
        __syncthreads();
        half8 a[4], b[4];
        #pragma unroll
        for (int i = 0; i < 4; ++i) a[i] = *(const half8*)&As[wm + i*16 + lm][quad*8];
        #pragma unroll
        for (int j = 0; j < 4; ++j) b[j] = *(const half8*)&Bs[wn + j*16 + lm][quad*8];
        #pragma unroll
        for (int i = 0; i < 4; ++i)
            #pragma unroll
            for (int j = 0; j < 4; ++j)
                acc[i][j] = __builtin_amdgcn_mfma_f32_16x16x32_f16(a[i], b[j], acc[i][j], 0, 0, 0);
        __syncthreads();
    }

    if (t < 128) { ssum[t] = 0.f; ssq[t] = 0.f; }
    __syncthreads();

    #pragma unroll
    for (int j = 0; j < 4; ++j) {
        int nl = wn + j*16 + lm;
        float psum = 0.f, psq = 0.f;
        #pragma unroll
        for (int i = 0; i < 4; ++i) {
            #pragma unroll
            for (int r = 0; r < 4; ++r) {
                int ml = wm + i*16 + quad*4 + r;
                float v = acc[i][j][r];
                C[(long)(m0 + ml) * ldc + n0 + nl] = v;
                psum += v; psq += v * v;
            }
        }
        atomicAdd(&ssum[nl], psum);
        atomicAdd(&ssq[nl], psq);
    }
    __syncthreads();
    if (t < 128) {
        atomicAdd(&gsum[n0 + t], ssum[t]);
        atomicAdd(&gsq[n0 + t],  ssq[t]);
    }
}

__global__ void bn_fin(const float* __restrict__ gsum, const float* __restrict__ gsq,
                       const float* __restrict__ g, const float* __restrict__ b,
                       float* __restrict__ a_out, float* __restrict__ s_out, int nch)
{
    int c = blockIdx.x * blockDim.x + threadIdx.x;
    if (c >= nch) return;
    float inv  = 1.f / (float)MROWS;
    float mean = gsum[c] * inv;
    float var  = gsq[c] * inv - mean * mean;
    float a    = g[c] * rsqrtf(var + EPSV);
    a_out[c] = a;
    s_out[c] = b[c] - mean * a;
}

// ---------------- attention: one block (8 waves) per (batch, head).
// After staging there are ZERO barriers: each wave owns whole 16-query tiles:
// S in registers -> in-register softmax -> per-wave LDS ps (C->A transpose) -> PV.
__global__ __launch_bounds__(512) void attn_kernel(
    const f16* __restrict__ hbuf, const float* __restrict__ a1, const float* __restrict__ s1,
    const float* __restrict__ bias_table, const int* __restrict__ idxs,
    f16* __restrict__ obuf)
{
    __shared__ f16   qs[208][40];
    __shared__ f16   ks[208][40];
    __shared__ f16   vT[128][256];      // XOR-block-swizzled V^T: blk' = (s>>3) ^ ((c>>3)&7)
    __shared__ f16   ps[8][16][232];    // per-wave P
    __shared__ float af[192], sf[192];
    __shared__ float biasr[196];

    const int t  = threadIdx.x;
    const int bb = blockIdx.x >> 3;
    const int hh = blockIdx.x & 7;
    const int wid = t >> 6, lane = t & 63, quad = lane >> 4, lm = lane & 15;

    if (t < 192) { af[t] = a1[hh * HPC + t]; sf[t] = s1[hh * HPC + t]; }
    if (t < 196) { biasr[t] = bias_table[hh * 196 + t]; }
    half8 z8 = {};
    // zero whole vT (swizzle scatters pad region), qs/ks pad rows, ps pad cols
    for (int i = t; i < 128 * 32; i += 512) *(half8*)&vT[i >> 5][(i & 31) * 8] = z8;
    for (int i = t; i < 12 * 40; i += 512) { qs[196 + i / 40][i % 40] = (f16)0.f;
                                             ks[196 + i / 40][i % 40] = (f16)0.f; }
    for (int i = t; i < 8 * 16 * 3; i += 512) {
        int w = i / 48, rr = (i / 3) & 15, c = (i % 3) * 8 + 208;
        *(half8*)&ps[w][rr][c] = z8;
    }
    __syncthreads();

    // stage q/k/v with BN1 affine; vT gets XOR-swizzled transpose (conflict-free writes)
    {
        int t8 = t & 7;
        for (int rr = t >> 3; rr < NTOK; rr += 64) {
            const f16* hrow = hbuf + (long)(bb * NTOK + rr) * HIDN + hh * HPC;
            #pragma unroll
            for (int cc = 0; cc < 3; ++cc) {
                int cb = (t8 + cc * 8) * 8;   // 0..184 step 8
                half8 raw = *(const half8*)(hrow + cb);
                f16 ov[8];
                #pragma unroll
                for (int e = 0; e < 8; ++e)
                    ov[e] = (f16)((float)raw[e] * af[cb + e] + sf[cb + e]);
                if (cb < 32) {
                    #pragma unroll
                    for (int e = 0; e < 8; ++e) qs[rr][cb + e] = ov[e];
                } else if (cb < 64) {
                    #pragma unroll
                    for (int e = 0; e < 8; ++e) ks[rr][cb - 32 + e] = ov[e];
                } else {
                    #pragma unroll
                    for (int e = 0; e < 8; ++e) {
                        int c = cb - 64 + e;
                        int pc = (rr & 7) | ((((rr >> 3) ^ ((c >> 3) & 7)) & 31) << 3);
                        vT[c][pc] = ov[e];
                    }
                }
            }
        }
    }
    __syncthreads();

    // each wave owns tiles mt = wid, wid+8
    for (int mt = wid; mt < 13; mt += 8) {
        // ---- S = q k^T (13 MFMAs, S in regs)
        half8 aq = *(const half8*)&qs[mt * 16 + lm][quad * 8];
        f4 sreg[13];
        #pragma unroll
        for (int nt = 0; nt < 13; ++nt) {
            half8 bk = *(const half8*)&ks[nt * 16 + lm][quad * 8];
            f4 z = {};
            sreg[nt] = __builtin_amdgcn_mfma_f32_16x16x32_f16(aq, bk, z, 0, 0, 0);
        }
        // ---- scale + bias + mask
        #pragma unroll
        for (int nt = 0; nt < 13; ++nt) {
            int kc = nt * 16 + lm;
            int ksafe = kc < 196 ? kc : 195;
            #pragma unroll
            for (int r = 0; r < 4; ++r) {
                int qrow = mt * 16 + quad * 4 + r;
                int qsafe = qrow < 196 ? qrow : 195;
                float bias_v = biasr[idxs[qsafe * 196 + ksafe]];
                float sv = sreg[nt][r] * SCALEV + bias_v;
                sreg[nt][r] = (kc < 196) ? sv : -1e30f;
            }
        }
        // ---- in-register softmax (16-lane quad groups hold one row)
        float rinv[4];
        #pragma unroll
        for (int r = 0; r < 4; ++r) {
            float m = sreg[0][r];
            #pragma unroll
            for (int nt = 1; nt < 13; ++nt) m = fmaxf(m, sreg[nt][r]);
            #pragma unroll
            for (int d = 1; d < 16; d <<= 1) m = fmaxf(m, __shfl_xor(m, d));
            float s = 0.f;
            #pragma unroll
            for (int nt = 0; nt < 13; ++nt) {
                float e = __expf(sreg[nt][r] - m);
                sreg[nt][r] = e;
                s += e;
            }
            #pragma unroll
            for (int d = 1; d < 16; d <<= 1) s += __shfl_xor(s, d);
            rinv[r] = 1.f / s;
        }
        // ---- P -> per-wave LDS (C-layout write)
        #pragma unroll
        for (int nt = 0; nt < 13; ++nt)
            #pragma unroll
            for (int r = 0; r < 4; ++r)
                ps[wid][quad * 4 + r][nt * 16 + lm] = (f16)(sreg[nt][r] * rinv[r]);

        // ---- O = P V (A-frags hoisted), hard-swish fused
        half8 ap[7];
        #pragma unroll
        for (int ks7 = 0; ks7 < 7; ++ks7)
            ap[ks7] = *(const half8*)&ps[wid][lm][ks7 * 32 + quad * 8];
        #pragma unroll
        for (int ct = 0; ct < 8; ++ct) {
            int c = ct * 16 + lm;
            int cswz = (c >> 3) & 7;
            f4 oa = {};
            #pragma unroll
            for (int ks7 = 0; ks7 < 7; ++ks7) {
                int pc = (((ks7 * 4 + quad) ^ cswz) & 31) << 3;
                half8 bv = *(const half8*)&vT[c][pc];
                oa = __builtin_amdgcn_mfma_f32_16x16x32_f16(ap[ks7], bv, oa, 0, 0, 0);
            }
            #pragma unroll
            for (int r = 0; r < 4; ++r) {
                int qrow = mt * 16 + quad * 4 + r;
                if (qrow < 196) {
                    float v  = oa[r];
                    float hs = v * fminf(fmaxf(v + 3.f, 0.f), 6.f) * (1.f / 6.f);
                    obuf[(long)(bb * NTOK + qrow) * DHD + hh * 128 + c] = (f16)hs;
                }
            }
        }
    }
}

__global__ __launch_bounds__(256) void bn_apply(
    float* __restrict__ out, const float* __restrict__ a2, const float* __restrict__ s2)
{
    __shared__ float aL[256], sL[256];
    int t = threadIdx.x;
    aL[t] = a2[t]; sL[t] = s2[t];
    __syncthreads();
    long total = (long)MROWS * 256 / 4;
    for (long i = (long)blockIdx.x * 256 + t; i < total; i += (long)gridDim.x * 256) {
        float4 v = *(float4*)&out[i * 4];
        int cb = (int)((i * 4) & 255);
        v.x = v.x * aL[cb + 0] + sL[cb + 0];
        v.y = v.y * aL[cb + 1] + sL[cb + 1];
        v.z = v.z * aL[cb + 2] + sL[cb + 2];
        v.w = v.w * aL[cb + 3] + sL[cb + 3];
        *(float4*)&out[i * 4] = v;
    }
}

extern "C" void kernel_launch(void* const* d_in, const int* in_sizes, int n_in,
                              void* d_out, int out_size, void* d_ws, size_t ws_size,
                              hipStream_t stream)
{
    (void)in_sizes; (void)n_in; (void)out_size; (void)ws_size;
    const float* x          = (const float*)d_in[0];
    const float* Wqkv       = (const float*)d_in[1];
    const float* g1         = (const float*)d_in[2];
    const float* b1         = (const float*)d_in[3];
    const float* bias_table = (const float*)d_in[4];
    const float* Wproj      = (const float*)d_in[5];
    const float* g2         = (const float*)d_in[6];
    const float* b2         = (const float*)d_in[7];
    const int*   idxs       = (const int*)d_in[8];
    float*       out        = (float*)d_out;

    char* ws = (char*)d_ws;
    f16* hbuf = (f16*)ws;                                 // [0, 154,140,672)
    f16* obuf = (f16*)(ws + 154140672LL);                 // [154,140,672, 256,901,120)
    // xh/wqh overlay obuf's region (dead before attn writes obuf)
    f16* xh   = (f16*)(ws + 154140672LL);                 // 25,690,112 B
    f16* wqh  = (f16*)(ws + 154140672LL + 25690112LL);    // 786,432 B
    // wph overlays hbuf (written after attn has consumed hbuf)
    f16* wph  = (f16*)ws;
    float* stats = (float*)(ws + 256901120LL);
    float* gsum1 = stats;            float* gsq1 = stats + 1536;
    float* gsum2 = stats + 3072;     float* gsq2 = stats + 3328;
    float* a1 = stats + 3584;        float* s1 = a1 + 1536;
    float* a2 = s1 + 1536;           float* s2 = a2 + 256;

    hipMemsetAsync(stats, 0, 3584 * sizeof(float), stream);

    // pre-convert x and Wqkv to f16
    cvt_f32_f16<<<12544, 256, 0, stream>>>(x, xh, 3211264);      // 50176*256/4
    cvt_f32_f16<<<384,   256, 0, stream>>>(Wqkv, wqh, 98304);    // 1536*256/4

    gemm1_qkv<<<dim3(392, 12), 256, 0, stream>>>(xh, wqh, hbuf, gsum1, gsq1);
    bn_fin<<<6, 256, 0, stream>>>(gsum1, gsq1, g1, b1, a1, s1, 1536);

    attn_kernel<<<2048, 512, 0, stream>>>(hbuf, a1, s1, bias_table, idxs, obuf);

    // hbuf dead now; convert Wproj into its space
    cvt_f32_f16<<<256, 256, 0, stream>>>(Wproj, wph, 65536);     // 256*1024/4

    gemm2_proj<<<dim3(392, 2), 256, 0, stream>>>(obuf, wph, out, gsum2, gsq2);
    bn_fin<<<1, 256, 0, stream>>>(gsum2, gsq2, g2, b2, a2, s2, 256);

    bn_apply<<<1024, 256, 0, stream>>>(out, a2, s2);
}

// Round 4
// 485.704 us; speedup vs baseline: 1.4955x; 1.0535x over previous
//
#include <hip/hip_runtime.h>

typedef _Float16 f16;
typedef __attribute__((ext_vector_type(8))) _Float16 half8;   // MFMA A/B frag (4 VGPRs)
typedef __attribute__((ext_vector_type(4))) _Float16 half4;
typedef __attribute__((ext_vector_type(4))) float   f4;       // MFMA C/D

#define NTOK   196
#define MROWS  50176            // 256 * 196
#define HIDN   1536
#define HPC    192              // per-head channels in h (q32|k32|v128)
#define DHD    1024             // H * 128
#define EPSV   1e-5f
#define SCALEV 0.17677669529663687f

// rotation swizzle: spreads banks for reads (row bits 0-3) AND writes (row bits 3-5)
__device__ inline int swz8(int row) { return (((row & 7) ^ ((row >> 3) & 7))) * 8; }

// ---------------- f32 -> f16 convert (vectorized)
__global__ void cvt_f32_f16(const float* __restrict__ src, f16* __restrict__ dst, int n4)
{
    int i = blockIdx.x * blockDim.x + threadIdx.x;
    if (i < n4) {
        float4 v = *(const float4*)&src[i * 4];
        half4 h = { (f16)v.x, (f16)v.y, (f16)v.z, (f16)v.w };
        *(half4*)&dst[i * 4] = h;
    }
}

// ---------------- GEMM1: h = x @ Wqkv^T  (f16 in, f16 out + BN stats)
__global__ __launch_bounds__(256) void gemm1_qkv(
    const f16* __restrict__ A, const f16* __restrict__ B,
    f16* __restrict__ C, float* __restrict__ gsum, float* __restrict__ gsq)
{
    const int K = 256, ldc = HIDN;
    __shared__ f16 As[128][40];
    __shared__ f16 Bs[128][40];
    __shared__ float ssum[128], ssq[128];

    const int t = threadIdx.x;
    const int m0 = blockIdx.x * 128, n0 = blockIdx.y * 128;
    const int wid = t >> 6, lane = t & 63, quad = lane >> 4, lm = lane & 15;
    const int wm = (wid >> 1) * 64, wn = (wid & 1) * 64;

    f4 acc[4][4] = {};

    for (int k0 = 0; k0 < K; k0 += 32) {
        #pragma unroll
        for (int s = 0; s < 2; ++s) {
            int ch = t + s * 256;              // 0..511
            int r = ch >> 2, c8 = (ch & 3) * 8;
            *(half8*)&As[r][c8] = *(const half8*)&A[(long)(m0 + r) * K + k0 + c8];
            *(half8*)&Bs[r][c8] = *(const half8*)&B[(long)(n0 + r) * K + k0 + c8];
        }
        __syncthreads();
        half8 a[4], b[4];
        #pragma unroll
        for (int i = 0; i < 4; ++i) a[i] = *(const half8*)&As[wm + i*16 + lm][quad*8];
        #pragma unroll
        for (int j = 0; j < 4; ++j) b[j] = *(const half8*)&Bs[wn + j*16 + lm][quad*8];
        #pragma unroll
        for (int i = 0; i < 4; ++i)
            #pragma unroll
            for (int j = 0; j < 4; ++j)
                acc[i][j] = __builtin_amdgcn_mfma_f32_16x16x32_f16(a[i], b[j], acc[i][j], 0, 0, 0);
        __syncthreads();
    }

    if (t < 128) { ssum[t] = 0.f; ssq[t] = 0.f; }
    __syncthreads();

    #pragma unroll
    for (int j = 0; j < 4; ++j) {
        int nl = wn + j*16 + lm;
        float psum = 0.f, psq = 0.f;
        #pragma unroll
        for (int i = 0; i < 4; ++i) {
            #pragma unroll
            for (int r = 0; r < 4; ++r) {
                int ml = wm + i*16 + quad*4 + r;
                float v = acc[i][j][r];
                f16 uh = (f16)v;
                float vb = (float)uh;
                C[(long)(m0 + ml) * ldc + n0 + nl] = uh;
                psum += vb; psq += vb * vb;
            }
        }
        atomicAdd(&ssum[nl], psum);
        atomicAdd(&ssq[nl], psq);
    }
    __syncthreads();
    if (t < 128) {
        atomicAdd(&gsum[n0 + t], ssum[t]);
        atomicAdd(&gsq[n0 + t],  ssq[t]);
    }
}

// ---------------- GEMM2: p = o @ Wproj^T  (f16 in, f32 out + BN stats)
__global__ __launch_bounds__(256) void gemm2_proj(
    const f16* __restrict__ A, const f16* __restrict__ B,
    float* __restrict__ C, float* __restrict__ gsum, float* __restrict__ gsq)
{
    const int K = 1024, ldc = 256;
    __shared__ f16 As[128][40];
    __shared__ f16 Bs[128][40];
    __shared__ float ssum[128], ssq[128];

    const int t = threadIdx.x;
    const int m0 = blockIdx.x * 128, n0 = blockIdx.y * 128;
    const int wid = t >> 6, lane = t & 63, quad = lane >> 4, lm = lane & 15;
    const int wm = (wid >> 1) * 64, wn = (wid & 1) * 64;

    f4 acc[4][4] = {};

    for (int k0 = 0; k0 < K; k0 += 32) {
        #pragma unroll
        for (int s = 0; s < 2; ++s) {
            int ch = t + s * 256;
            int r = ch >> 2, c8 = (ch & 3) * 8;
            *(half8*)&As[r][c8] = *(const half8*)&A[(long)(m0 + r) * K + k0 + c8];
            *(half8*)&Bs[r][c8] = *(const half8*)&B[(long)(n0 + r) * K + k0 + c8];
        }
        __syncthreads();
        half8 a[4], b[4];
        #pragma unroll
        for (int i = 0; i < 4; ++i) a[i] = *(const half8*)&As[wm + i*16 + lm][quad*8];
        #pragma unroll
        for (int j = 0; j < 4; ++j) b[j] = *(const half8*)&Bs[wn + j*16 + lm][quad*8];
        #pragma unroll
        for (int i = 0; i < 4; ++i)
            #pragma unroll
            for (int j = 0; j < 4; ++j)
                acc[i][j] = __builtin_amdgcn_mfma_f32_16x16x32_f16(a[i], b[j], acc[i][j], 0, 0, 0);
        __syncthreads();
    }

    if (t < 128) { ssum[t] = 0.f; ssq[t] = 0.f; }
    __syncthreads();

    #pragma unroll
    for (int j = 0; j < 4; ++j) {
        int nl = wn + j*16 + lm;
        float psum = 0.f, psq = 0.f;
        #pragma unroll
        for (int i = 0; i < 4; ++i) {
            #pragma unroll
            for (int r = 0; r < 4; ++r) {
                int ml = wm + i*16 + quad*4 + r;
                float v = acc[i][j][r];
                C[(long)(m0 + ml) * ldc + n0 + nl] = v;
                psum += v; psq += v * v;
            }
        }
        atomicAdd(&ssum[nl], psum);
        atomicAdd(&ssq[nl], psq);
    }
    __syncthreads();
    if (t < 128) {
        atomicAdd(&gsum[n0 + t], ssum[t]);
        atomicAdd(&gsq[n0 + t],  ssq[t]);
    }
}

__global__ void bn_fin(const float* __restrict__ gsum, const float* __restrict__ gsq,
                       const float* __restrict__ g, const float* __restrict__ b,
                       float* __restrict__ a_out, float* __restrict__ s_out, int nch)
{
    int c = blockIdx.x * blockDim.x + threadIdx.x;
    if (c >= nch) return;
    float inv  = 1.f / (float)MROWS;
    float mean = gsum[c] * inv;
    float var  = gsq[c] * inv - mean * mean;
    float a    = g[c] * rsqrtf(var + EPSV);
    a_out[c] = a;
    s_out[c] = b[c] - mean * a;
}

// ---------------- attention: one block (8 waves) per (batch, head).
// Barrier-free after staging. Rotation-swizzled LDS (conflict-free reads AND writes).
// Waves 0-4 own the mt pair {wid, wid+8}: each vT B-frag read feeds 2 MFMAs.
__global__ __launch_bounds__(512) void attn_kernel(
    const f16* __restrict__ hbuf, const float* __restrict__ a1, const float* __restrict__ s1,
    const float* __restrict__ bias_table, const int* __restrict__ idxs,
    f16* __restrict__ obuf)
{
    __shared__ f16   qs[208][32];       // 13312 B, rotation-swizzled k
    __shared__ f16   ks[208][32];       // 13312 B
    __shared__ f16   vT[128][256];      // 65536 B, V^T rows=channel, swizzled keys
    __shared__ f16   ps[8][16][256];    // 65536 B, per-wave P, swizzled keys
    __shared__ float af[192], sf[192];
    __shared__ float biasr[196];

    const int t  = threadIdx.x;
    const int bb = blockIdx.x >> 3;
    const int hh = blockIdx.x & 7;
    const int wid = t >> 6, lane = t & 63, quad = lane >> 4, lm = lane & 15;

    if (t < 192) { af[t] = a1[hh * HPC + t]; sf[t] = s1[hh * HPC + t]; }
    if (t < 196) { biasr[t] = bias_table[hh * 196 + t]; }
    half8 z8 = {};
    // zero vT and ps fully (swizzle scatters pad slots); qs/ks pad rows
    for (int i = t; i < 4096; i += 512) *(half8*)&vT[i >> 5][(i & 31) * 8] = z8;
    for (int i = t; i < 4096; i += 512) *(half8*)&ps[i >> 9][(i >> 5) & 15][(i & 31) * 8] = z8;
    for (int i = t; i < 12 * 32; i += 512) { qs[196 + (i >> 5)][i & 31] = (f16)0.f;
                                             ks[196 + (i >> 5)][i & 31] = (f16)0.f; }
    __syncthreads();

    // stage q/k/v with BN1 affine, rotation-swizzled placement
    {
        int t8 = t & 7;
        for (int rr = t >> 3; rr < NTOK; rr += 64) {
            const f16* hrow = hbuf + (long)(bb * NTOK + rr) * HIDN + hh * HPC;
            int sr = swz8(rr);
            #pragma unroll
            for (int cc = 0; cc < 3; ++cc) {
                int cb = (t8 + cc * 8) * 8;   // 0..184 step 8
                half8 raw = *(const half8*)(hrow + cb);
                f16 ov[8];
                #pragma unroll
                for (int e = 0; e < 8; ++e)
                    ov[e] = (f16)((float)raw[e] * af[cb + e] + sf[cb + e]);
                if (cb < 32) {
                    #pragma unroll
                    for (int e = 0; e < 8; ++e) qs[rr][(cb + e + sr) & 31] = ov[e];
                } else if (cb < 64) {
                    #pragma unroll
                    for (int e = 0; e < 8; ++e) ks[rr][(cb - 32 + e + sr) & 31] = ov[e];
                } else {
                    #pragma unroll
                    for (int e = 0; e < 8; ++e) {
                        int c = cb - 64 + e;
                        vT[c][(rr + swz8(c)) & 255] = ov[e];
                    }
                }
            }
        }
    }
    __syncthreads();

    // waves 0-4 own {wid, wid+8}; waves 5-7 own {wid}
    const int nmt = (wid + 8 < 13) ? 2 : 1;
    half8 ap[2][7];

    for (int pass = 0; pass < nmt; ++pass) {
        const int mt = wid + pass * 8;
        // ---- S = q k^T (13 MFMAs, S in regs)
        int qrowA = mt * 16 + lm;
        half8 aq = *(const half8*)&qs[qrowA][(quad * 8 + swz8(qrowA)) & 31];
        f4 sreg[13];
        #pragma unroll
        for (int nt = 0; nt < 13; ++nt) {
            int krow = nt * 16 + lm;
            half8 bk = *(const half8*)&ks[krow][(quad * 8 + swz8(krow)) & 31];
            f4 z = {};
            sreg[nt] = __builtin_amdgcn_mfma_f32_16x16x32_f16(aq, bk, z, 0, 0, 0);
        }
        // ---- scale + bias + mask
        #pragma unroll
        for (int nt = 0; nt < 13; ++nt) {
            int kc = nt * 16 + lm;
            int ksafe = kc < 196 ? kc : 195;
            #pragma unroll
            for (int r = 0; r < 4; ++r) {
                int qrow = mt * 16 + quad * 4 + r;
                int qsafe = qrow < 196 ? qrow : 195;
                float bias_v = biasr[idxs[qsafe * 196 + ksafe]];
                float sv = sreg[nt][r] * SCALEV + bias_v;
                sreg[nt][r] = (kc < 196) ? sv : -1e30f;
            }
        }
        // ---- in-register softmax (16-lane groups per row)
        float rinv[4];
        #pragma unroll
        for (int r = 0; r < 4; ++r) {
            float m = sreg[0][r];
            #pragma unroll
            for (int nt = 1; nt < 13; ++nt) m = fmaxf(m, sreg[nt][r]);
            #pragma unroll
            for (int d = 1; d < 16; d <<= 1) m = fmaxf(m, __shfl_xor(m, d));
            float s = 0.f;
            #pragma unroll
            for (int nt = 0; nt < 13; ++nt) {
                float e = __expf(sreg[nt][r] - m);
                sreg[nt][r] = e;
                s += e;
            }
            #pragma unroll
            for (int d = 1; d < 16; d <<= 1) s += __shfl_xor(s, d);
            rinv[r] = 1.f / s;
        }
        // ---- P -> per-wave LDS (swizzled), then A-frags into registers
        #pragma unroll
        for (int nt = 0; nt < 13; ++nt)
            #pragma unroll
            for (int r = 0; r < 4; ++r) {
                int q = quad * 4 + r;
                ps[wid][q][(nt * 16 + lm + swz8(q)) & 255] = (f16)(sreg[nt][r] * rinv[r]);
            }
        #pragma unroll
        for (int k7 = 0; k7 < 7; ++k7)
            ap[pass][k7] = *(const half8*)&ps[wid][lm][(k7 * 32 + quad * 8 + swz8(lm)) & 255];
    }

    // ---- O = P V fused over the mt pair: each bv read feeds nmt MFMAs
    #pragma unroll
    for (int ct = 0; ct < 8; ++ct) {
        int c = ct * 16 + lm;
        int sc = swz8(c);
        f4 oa0 = {}, oa1 = {};
        #pragma unroll
        for (int k7 = 0; k7 < 7; ++k7) {
            half8 bv = *(const half8*)&vT[c][(k7 * 32 + quad * 8 + sc) & 255];
            oa0 = __builtin_amdgcn_mfma_f32_16x16x32_f16(ap[0][k7], bv, oa0, 0, 0, 0);
            if (nmt == 2)
                oa1 = __builtin_amdgcn_mfma_f32_16x16x32_f16(ap[1][k7], bv, oa1, 0, 0, 0);
        }
        #pragma unroll
        for (int r = 0; r < 4; ++r) {
            int qrow = wid * 16 + quad * 4 + r;
            if (qrow < 196) {
                float v  = oa0[r];
                float hs = v * fminf(fmaxf(v + 3.f, 0.f), 6.f) * (1.f / 6.f);
                obuf[(long)(bb * NTOK + qrow) * DHD + hh * 128 + c] = (f16)hs;
            }
        }
        if (nmt == 2) {
            #pragma unroll
            for (int r = 0; r < 4; ++r) {
                int qrow = (wid + 8) * 16 + quad * 4 + r;
                if (qrow < 196) {
                    float v  = oa1[r];
                    float hs = v * fminf(fmaxf(v + 3.f, 0.f), 6.f) * (1.f / 6.f);
                    obuf[(long)(bb * NTOK + qrow) * DHD + hh * 128 + c] = (f16)hs;
                }
            }
        }
    }
}

__global__ __launch_bounds__(256) void bn_apply(
    float* __restrict__ out, const float* __restrict__ a2, const float* __restrict__ s2)
{
    __shared__ float aL[256], sL[256];
    int t = threadIdx.x;
    aL[t] = a2[t]; sL[t] = s2[t];
    __syncthreads();
    long total = (long)MROWS * 256 / 4;
    for (long i = (long)blockIdx.x * 256 + t; i < total; i += (long)gridDim.x * 256) {
        float4 v = *(float4*)&out[i * 4];
        int cb = (int)((i * 4) & 255);
        v.x = v.x * aL[cb + 0] + sL[cb + 0];
        v.y = v.y * aL[cb + 1] + sL[cb + 1];
        v.z = v.z * aL[cb + 2] + sL[cb + 2];
        v.w = v.w * aL[cb + 3] + sL[cb + 3];
        *(float4*)&out[i * 4] = v;
    }
}

extern "C" void kernel_launch(void* const* d_in, const int* in_sizes, int n_in,
                              void* d_out, int out_size, void* d_ws, size_t ws_size,
                              hipStream_t stream)
{
    (void)in_sizes; (void)n_in; (void)out_size; (void)ws_size;
    const float* x          = (const float*)d_in[0];
    const float* Wqkv       = (const float*)d_in[1];
    const float* g1         = (const float*)d_in[2];
    const float* b1         = (const float*)d_in[3];
    const float* bias_table = (const float*)d_in[4];
    const float* Wproj      = (const float*)d_in[5];
    const float* g2         = (const float*)d_in[6];
    const float* b2         = (const float*)d_in[7];
    const int*   idxs       = (const int*)d_in[8];
    float*       out        = (float*)d_out;

    char* ws = (char*)d_ws;
    f16* hbuf = (f16*)ws;                                 // [0, 154,140,672)
    f16* obuf = (f16*)(ws + 154140672LL);                 // [154,140,672, 256,901,120)
    f16* xh   = (f16*)(ws + 154140672LL);                 // overlay (dead before attn)
    f16* wqh  = (f16*)(ws + 154140672LL + 25690112LL);
    f16* wph  = (f16*)ws;                                 // overlay hbuf (dead after attn)
    float* stats = (float*)(ws + 256901120LL);
    float* gsum1 = stats;            float* gsq1 = stats + 1536;
    float* gsum2 = stats + 3072;     float* gsq2 = stats + 3328;
    float* a1 = stats + 3584;        float* s1 = a1 + 1536;
    float* a2 = s1 + 1536;           float* s2 = a2 + 256;

    hipMemsetAsync(stats, 0, 3584 * sizeof(float), stream);

    cvt_f32_f16<<<12544, 256, 0, stream>>>(x, xh, 3211264);
    cvt_f32_f16<<<384,   256, 0, stream>>>(Wqkv, wqh, 98304);

    gemm1_qkv<<<dim3(392, 12), 256, 0, stream>>>(xh, wqh, hbuf, gsum1, gsq1);
    bn_fin<<<6, 256, 0, stream>>>(gsum1, gsq1, g1, b1, a1, s1, 1536);

    attn_kernel<<<2048, 512, 0, stream>>>(hbuf, a1, s1, bias_table, idxs, obuf);

    cvt_f32_f16<<<256, 256, 0, stream>>>(Wproj, wph, 65536);

    gemm2_proj<<<dim3(392, 2), 256, 0, stream>>>(obuf, wph, out, gsum2, gsq2);
    bn_fin<<<1, 256, 0, stream>>>(gsum2, gsq2, g2, b2, a2, s2, 256);

    bn_apply<<<1024, 256, 0, stream>>>(out, a2, s2);
}

// Round 5
// 474.877 us; speedup vs baseline: 1.5296x; 1.0228x over previous
//
#include <hip/hip_runtime.h>

typedef _Float16 f16;
typedef __attribute__((ext_vector_type(8))) _Float16 half8;   // MFMA A/B frag (4 VGPRs)
typedef __attribute__((ext_vector_type(4))) _Float16 half4;
typedef __attribute__((ext_vector_type(4))) float   f4;       // MFMA C/D

#define NTOK   196
#define MROWS  50176            // 256 * 196
#define HIDN   1536
#define HPC    192              // per-head channels in h (q32|k32|v128)
#define DHD    1024             // H * 128
#define EPSV   1e-5f
#define SCALEV 0.17677669529663687f

// async global->LDS, 16B per lane; LDS dest is wave-uniform base + lane*16
#define GLD16(gp, lp) __builtin_amdgcn_global_load_lds( \
    (const __attribute__((address_space(1))) unsigned int*)(gp), \
    (__attribute__((address_space(3))) unsigned int*)(lp), 16, 0, 0)

// rotation swizzle: spreads banks for reads (row bits 0-3) AND writes (row bits 3-5)
__device__ inline int swz8(int row) { return (((row & 7) ^ ((row >> 3) & 7))) * 8; }

// ---------------- f32 -> f16 convert (vectorized)
__global__ void cvt_f32_f16(const float* __restrict__ src, f16* __restrict__ dst, int n4)
{
    int i = blockIdx.x * blockDim.x + threadIdx.x;
    if (i < n4) {
        float4 v = *(const float4*)&src[i * 4];
        half4 h = { (f16)v.x, (f16)v.y, (f16)v.z, (f16)v.w };
        *(half4*)&dst[i * 4] = h;
    }
}

// ---------------- bias_full[h][208][224] f16: idxs gather resolved once; pad = -30000 (mask baked in)
__global__ void build_bias(const float* __restrict__ bt, const int* __restrict__ idxs,
                           f16* __restrict__ bf)
{
    int i = blockIdx.x * 256 + threadIdx.x;
    if (i >= 8 * 208 * 224) return;
    int k = i % 224, q = (i / 224) % 208, h = i / (224 * 208);
    float v = -30000.f;
    if (q < NTOK && k < NTOK) v = bt[h * NTOK + idxs[q * NTOK + k]];
    bf[i] = (f16)v;
}

// ---------------- GEMM1: h = x @ Wqkv^T  (f16 in, f16 out + BN stats), global_load_lds staging
__global__ __launch_bounds__(256) void gemm1_qkv(
    const f16* __restrict__ A, const f16* __restrict__ B,
    f16* __restrict__ C, float* __restrict__ gsum, float* __restrict__ gsq)
{
    const int K = 256, ldc = HIDN;
    __shared__ f16 As[128 * 32];      // unpadded: required by global_load_lds layout
    __shared__ f16 Bs[128 * 32];
    __shared__ float ssum[128], ssq[128];

    const int t = threadIdx.x;
    const int m0 = blockIdx.x * 128, n0 = blockIdx.y * 128;
    const int wid = t >> 6, lane = t & 63, quad = lane >> 4, lm = lane & 15;
    const int wm = (wid >> 1) * 64, wn = (wid & 1) * 64;

    // staging geometry: wave w slot s covers rows w*32+s*16 .. +15 (lane r>>2), col8 = (lane&3)*8
    const int lr = lane >> 2, lc = (lane & 3) * 8;
    f16* As0 = &As[(wid * 2 + 0) * 512];
    f16* As1 = &As[(wid * 2 + 1) * 512];
    f16* Bs0 = &Bs[(wid * 2 + 0) * 512];
    f16* Bs1 = &Bs[(wid * 2 + 1) * 512];
    const f16* Ab = A + (long)(m0 + wid * 32 + lr) * K + lc;
    const f16* Bb = B + (long)(n0 + wid * 32 + lr) * K + lc;

    f4 acc[4][4] = {};

    for (int k0 = 0; k0 < K; k0 += 32) {
        GLD16(Ab + k0,          As0);
        GLD16(Ab + 16 * K + k0, As1);
        GLD16(Bb + k0,          Bs0);
        GLD16(Bb + 16 * K + k0, Bs1);
        __syncthreads();
        half8 a[4], b[4];
        #pragma unroll
        for (int i = 0; i < 4; ++i) a[i] = *(const half8*)&As[(wm + i*16 + lm) * 32 + quad * 8];
        #pragma unroll
        for (int j = 0; j < 4; ++j) b[j] = *(const half8*)&Bs[(wn + j*16 + lm) * 32 + quad * 8];
        #pragma unroll
        for (int i = 0; i < 4; ++i)
            #pragma unroll
            for (int j = 0; j < 4; ++j)
                acc[i][j] = __builtin_amdgcn_mfma_f32_16x16x32_f16(a[i], b[j], acc[i][j], 0, 0, 0);
        __syncthreads();
    }

    if (t < 128) { ssum[t] = 0.f; ssq[t] = 0.f; }
    __syncthreads();

    #pragma unroll
    for (int j = 0; j < 4; ++j) {
        int nl = wn + j*16 + lm;
        float psum = 0.f, psq = 0.f;
        #pragma unroll
        for (int i = 0; i < 4; ++i) {
            #pragma unroll
            for (int r = 0; r < 4; ++r) {
                int ml = wm + i*16 + quad*4 + r;
                float v = acc[i][j][r];
                f16 uh = (f16)v;
                float vb = (float)uh;
                C[(long)(m0 + ml) * ldc + n0 + nl] = uh;
                psum += vb; psq += vb * vb;
            }
        }
        atomicAdd(&ssum[nl], psum);
        atomicAdd(&ssq[nl], psq);
    }
    __syncthreads();
    if (t < 128) {
        atomicAdd(&gsum[n0 + t], ssum[t]);
        atomicAdd(&gsq[n0 + t],  ssq[t]);
    }
}

// ---------------- GEMM2: p = o @ Wproj^T  (f16 in, f32 out + BN stats), global_load_lds staging
__global__ __launch_bounds__(256) void gemm2_proj(
    const f16* __restrict__ A, const f16* __restrict__ B,
    float* __restrict__ C, float* __restrict__ gsum, float* __restrict__ gsq)
{
    const int K = 1024, ldc = 256;
    __shared__ f16 As[128 * 32];
    __shared__ f16 Bs[128 * 32];
    __shared__ float ssum[128], ssq[128];

    const int t = threadIdx.x;
    const int m0 = blockIdx.x * 128, n0 = blockIdx.y * 128;
    const int wid = t >> 6, lane = t & 63, quad = lane >> 4, lm = lane & 15;
    const int wm = (wid >> 1) * 64, wn = (wid & 1) * 64;

    const int lr = lane >> 2, lc = (lane & 3) * 8;
    f16* As0 = &As[(wid * 2 + 0) * 512];
    f16* As1 = &As[(wid * 2 + 1) * 512];
    f16* Bs0 = &Bs[(wid * 2 + 0) * 512];
    f16* Bs1 = &Bs[(wid * 2 + 1) * 512];
    const f16* Ab = A + (long)(m0 + wid * 32 + lr) * K + lc;
    const f16* Bb = B + (long)(n0 + wid * 32 + lr) * K + lc;

    f4 acc[4][4] = {};

    for (int k0 = 0; k0 < K; k0 += 32) {
        GLD16(Ab + k0,          As0);
        GLD16(Ab + 16 * K + k0, As1);
        GLD16(Bb + k0,          Bs0);
        GLD16(Bb + 16 * K + k0, Bs1);
        __syncthreads();
        half8 a[4], b[4];
        #pragma unroll
        for (int i = 0; i < 4; ++i) a[i] = *(const half8*)&As[(wm + i*16 + lm) * 32 + quad * 8];
        #pragma unroll
        for (int j = 0; j < 4; ++j) b[j] = *(const half8*)&Bs[(wn + j*16 + lm) * 32 + quad * 8];
        #pragma unroll
        for (int i = 0; i < 4; ++i)
            #pragma unroll
            for (int j = 0; j < 4; ++j)
                acc[i][j] = __builtin_amdgcn_mfma_f32_16x16x32_f16(a[i], b[j], acc[i][j], 0, 0, 0);
        __syncthreads();
    }

    if (t < 128) { ssum[t] = 0.f; ssq[t] = 0.f; }
    __syncthreads();

    #pragma unroll
    for (int j = 0; j < 4; ++j) {
        int nl = wn + j*16 + lm;
        float psum = 0.f, psq = 0.f;
        #pragma unroll
        for (int i = 0; i < 4; ++i) {
            #pragma unroll
            for (int r = 0; r < 4; ++r) {
                int ml = wm + i*16 + quad*4 + r;
                float v = acc[i][j][r];
                C[(long)(m0 + ml) * ldc + n0 + nl] = v;
                psum += v; psq += v * v;
            }
        }
        atomicAdd(&ssum[nl], psum);
        atomicAdd(&ssq[nl], psq);
    }
    __syncthreads();
    if (t < 128) {
        atomicAdd(&gsum[n0 + t], ssum[t]);
        atomicAdd(&gsq[n0 + t],  ssq[t]);
    }
}

__global__ void bn_fin(const float* __restrict__ gsum, const float* __restrict__ gsq,
                       const float* __restrict__ g, const float* __restrict__ b,
                       float* __restrict__ a_out, float* __restrict__ s_out, int nch)
{
    int c = blockIdx.x * blockDim.x + threadIdx.x;
    if (c >= nch) return;
    float inv  = 1.f / (float)MROWS;
    float mean = gsum[c] * inv;
    float var  = gsq[c] * inv - mean * mean;
    float a    = g[c] * rsqrtf(var + EPSV);
    a_out[c] = a;
    s_out[c] = b[c] - mean * a;
}

// ---------------- attention: one block (8 waves) per (batch, head).
// Barrier-free after staging; rotation-swizzled LDS; bias from precomputed f16 table
// (mask baked into pad columns), waves 0-4 own mt pair {wid, wid+8} for vT B-reuse.
__global__ __launch_bounds__(512) void attn_kernel(
    const f16* __restrict__ hbuf, const float* __restrict__ a1, const float* __restrict__ s1,
    const f16* __restrict__ bf, f16* __restrict__ obuf)
{
    __shared__ f16   qs[208][32];
    __shared__ f16   ks[208][32];
    __shared__ f16   vT[128][256];
    __shared__ f16   ps[8][16][256];
    __shared__ float af[192], sf[192];

    const int t  = threadIdx.x;
    const int bb = blockIdx.x >> 3;
    const int hh = blockIdx.x & 7;
    const int wid = t >> 6, lane = t & 63, quad = lane >> 4, lm = lane & 15;

    if (t < 192) { af[t] = a1[hh * HPC + t]; sf[t] = s1[hh * HPC + t]; }
    half8 z8 = {};
    for (int i = t; i < 4096; i += 512) *(half8*)&vT[i >> 5][(i & 31) * 8] = z8;
    for (int i = t; i < 4096; i += 512) *(half8*)&ps[i >> 9][(i >> 5) & 15][(i & 31) * 8] = z8;
    for (int i = t; i < 12 * 32; i += 512) { qs[196 + (i >> 5)][i & 31] = (f16)0.f;
                                             ks[196 + (i >> 5)][i & 31] = (f16)0.f; }
    __syncthreads();

    // stage q/k/v with BN1 affine, rotation-swizzled placement
    {
        int t8 = t & 7;
        for (int rr = t >> 3; rr < NTOK; rr += 64) {
            const f16* hrow = hbuf + (long)(bb * NTOK + rr) * HIDN + hh * HPC;
            int sr = swz8(rr);
            #pragma unroll
            for (int cc = 0; cc < 3; ++cc) {
                int cb = (t8 + cc * 8) * 8;   // 0..184 step 8
                half8 raw = *(const half8*)(hrow + cb);
                f16 ov[8];
                #pragma unroll
                for (int e = 0; e < 8; ++e)
                    ov[e] = (f16)((float)raw[e] * af[cb + e] + sf[cb + e]);
                if (cb < 32) {
                    #pragma unroll
                    for (int e = 0; e < 8; ++e) qs[rr][(cb + e + sr) & 31] = ov[e];
                } else if (cb < 64) {
                    #pragma unroll
                    for (int e = 0; e < 8; ++e) ks[rr][(cb - 32 + e + sr) & 31] = ov[e];
                } else {
                    #pragma unroll
                    for (int e = 0; e < 8; ++e) {
                        int c = cb - 64 + e;
                        vT[c][(rr + swz8(c)) & 255] = ov[e];
                    }
                }
            }
        }
    }
    __syncthreads();

    const int nmt = (wid + 8 < 13) ? 2 : 1;
    half8 ap[2][7];
    const f16* bfh = bf + hh * 208 * 224;

    for (int pass = 0; pass < nmt; ++pass) {
        const int mt = wid + pass * 8;
        // ---- S = q k^T (13 MFMAs, S in regs)
        int qrowA = mt * 16 + lm;
        half8 aq = *(const half8*)&qs[qrowA][(quad * 8 + swz8(qrowA)) & 31];
        f4 sreg[13];
        #pragma unroll
        for (int nt = 0; nt < 13; ++nt) {
            int krow = nt * 16 + lm;
            half8 bk = *(const half8*)&ks[krow][(quad * 8 + swz8(krow)) & 31];
            f4 z = {};
            sreg[nt] = __builtin_amdgcn_mfma_f32_16x16x32_f16(aq, bk, z, 0, 0, 0);
        }
        // ---- scale + bias (mask baked into bias pad cols)
        #pragma unroll
        for (int nt = 0; nt < 13; ++nt) {
            int kc = nt * 16 + lm;
            #pragma unroll
            for (int r = 0; r < 4; ++r) {
                int qrow = mt * 16 + quad * 4 + r;
                float bias_v = (float)bfh[qrow * 224 + kc];
                sreg[nt][r] = sreg[nt][r] * SCALEV + bias_v;
            }
        }
        // ---- in-register softmax (16-lane groups per row)
        float rinv[4];
        #pragma unroll
        for (int r = 0; r < 4; ++r) {
            float m = sreg[0][r];
            #pragma unroll
            for (int nt = 1; nt < 13; ++nt) m = fmaxf(m, sreg[nt][r]);
            #pragma unroll
            for (int d = 1; d < 16; d <<= 1) m = fmaxf(m, __shfl_xor(m, d));
            float s = 0.f;
            #pragma unroll
            for (int nt = 0; nt < 13; ++nt) {
                float e = __expf(sreg[nt][r] - m);
                sreg[nt][r] = e;
                s += e;
            }
            #pragma unroll
            for (int d = 1; d < 16; d <<= 1) s += __shfl_xor(s, d);
            rinv[r] = 1.f / s;
        }
        // ---- P -> per-wave LDS (swizzled), then A-frags into registers
        #pragma unroll
        for (int nt = 0; nt < 13; ++nt)
            #pragma unroll
            for (int r = 0; r < 4; ++r) {
                int q = quad * 4 + r;
                ps[wid][q][(nt * 16 + lm + swz8(q)) & 255] = (f16)(sreg[nt][r] * rinv[r]);
            }
        #pragma unroll
        for (int k7 = 0; k7 < 7; ++k7)
            ap[pass][k7] = *(const half8*)&ps[wid][lm][(k7 * 32 + quad * 8 + swz8(lm)) & 255];
    }

    // ---- O = P V fused over the mt pair: each bv read feeds nmt MFMAs
    #pragma unroll
    for (int ct = 0; ct < 8; ++ct) {
        int c = ct * 16 + lm;
        int sc = swz8(c);
        f4 oa0 = {}, oa1 = {};
        #pragma unroll
        for (int k7 = 0; k7 < 7; ++k7) {
            half8 bv = *(const half8*)&vT[c][(k7 * 32 + quad * 8 + sc) & 255];
            oa0 = __builtin_amdgcn_mfma_f32_16x16x32_f16(ap[0][k7], bv, oa0, 0, 0, 0);
            if (nmt == 2)
                oa1 = __builtin_amdgcn_mfma_f32_16x16x32_f16(ap[1][k7], bv, oa1, 0, 0, 0);
        }
        #pragma unroll
        for (int r = 0; r < 4; ++r) {
            int qrow = wid * 16 + quad * 4 + r;
            if (qrow < 196) {
                float v  = oa0[r];
                float hs = v * fminf(fmaxf(v + 3.f, 0.f), 6.f) * (1.f / 6.f);
                obuf[(long)(bb * NTOK + qrow) * DHD + hh * 128 + c] = (f16)hs;
            }
        }
        if (nmt == 2) {
            #pragma unroll
            for (int r = 0; r < 4; ++r) {
                int qrow = (wid + 8) * 16 + quad * 4 + r;
                if (qrow < 196) {
                    float v  = oa1[r];
                    float hs = v * fminf(fmaxf(v + 3.f, 0.f), 6.f) * (1.f / 6.f);
                    obuf[(long)(bb * NTOK + qrow) * DHD + hh * 128 + c] = (f16)hs;
                }
            }
        }
    }
}

__global__ __launch_bounds__(256) void bn_apply(
    float* __restrict__ out, const float* __restrict__ a2, const float* __restrict__ s2)
{
    __shared__ float aL[256], sL[256];
    int t = threadIdx.x;
    aL[t] = a2[t]; sL[t] = s2[t];
    __syncthreads();
    long total = (long)MROWS * 256 / 4;
    for (long i = (long)blockIdx.x * 256 + t; i < total; i += (long)gridDim.x * 256) {
        float4 v = *(float4*)&out[i * 4];
        int cb = (int)((i * 4) & 255);
        v.x = v.x * aL[cb + 0] + sL[cb + 0];
        v.y = v.y * aL[cb + 1] + sL[cb + 1];
        v.z = v.z * aL[cb + 2] + sL[cb + 2];
        v.w = v.w * aL[cb + 3] + sL[cb + 3];
        *(float4*)&out[i * 4] = v;
    }
}

extern "C" void kernel_launch(void* const* d_in, const int* in_sizes, int n_in,
                              void* d_out, int out_size, void* d_ws, size_t ws_size,
                              hipStream_t stream)
{
    (void)in_sizes; (void)n_in; (void)out_size; (void)ws_size;
    const float* x          = (const float*)d_in[0];
    const float* Wqkv       = (const float*)d_in[1];
    const float* g1         = (const float*)d_in[2];
    const float* b1         = (const float*)d_in[3];
    const float* bias_table = (const float*)d_in[4];
    const float* Wproj      = (const float*)d_in[5];
    const float* g2         = (const float*)d_in[6];
    const float* b2         = (const float*)d_in[7];
    const int*   idxs       = (const int*)d_in[8];
    float*       out        = (float*)d_out;

    char* ws = (char*)d_ws;
    f16* hbuf = (f16*)ws;                                 // [0, 154,140,672)
    f16* obuf = (f16*)(ws + 154140672LL);                 // [154,140,672, 256,901,120)
    f16* xh   = (f16*)(ws + 154140672LL);                 // overlay (dead before attn)
    f16* wqh  = (f16*)(ws + 154140672LL + 25690112LL);
    f16* wph  = (f16*)ws;                                 // overlay hbuf (dead after attn)
    float* stats = (float*)(ws + 256901120LL);
    float* gsum1 = stats;            float* gsq1 = stats + 1536;
    float* gsum2 = stats + 3072;     float* gsq2 = stats + 3328;
    float* a1 = stats + 3584;        float* s1 = a1 + 1536;
    float* a2 = s1 + 1536;           float* s2 = a2 + 256;
    f16* bias_full = (f16*)(ws + 256901120LL + 65536LL);  // 8*208*224*2 = 745,472 B

    hipMemsetAsync(stats, 0, 3584 * sizeof(float), stream);

    cvt_f32_f16<<<12544, 256, 0, stream>>>(x, xh, 3211264);
    cvt_f32_f16<<<384,   256, 0, stream>>>(Wqkv, wqh, 98304);
    build_bias<<<1456, 256, 0, stream>>>(bias_table, idxs, bias_full);

    gemm1_qkv<<<dim3(392, 12), 256, 0, stream>>>(xh, wqh, hbuf, gsum1, gsq1);
    bn_fin<<<6, 256, 0, stream>>>(gsum1, gsq1, g1, b1, a1, s1, 1536);

    attn_kernel<<<2048, 512, 0, stream>>>(hbuf, a1, s1, bias_full, obuf);

    cvt_f32_f16<<<256, 256, 0, stream>>>(Wproj, wph, 65536);

    gemm2_proj<<<dim3(392, 2), 256, 0, stream>>>(obuf, wph, out, gsum2, gsq2);
    bn_fin<<<1, 256, 0, stream>>>(gsum2, gsq2, g2, b2, a2, s2, 256);

    bn_apply<<<1024, 256, 0, stream>>>(out, a2, s2);
}